// Round 13
// baseline (1388.115 us; speedup 1.0000x reference)
//
#include <hip/hip_runtime.h>
#include <hip/hip_bf16.h>

#define N_NODES 50000
#define N_EDGES 1600000
#define N_REL   20
#define N_BASIS 16
#define DIM     128

#define NBLK   ((N_NODES + 31) / 32)     // 1563 fused blocks (32 dst each)
#define KEYB   (N_REL * 32)              // 640 keys per dst-block
#define NBINS2 (NBLK * KEYB)             // 1,000,320 : key = (dst/32)*640 + r*32 + dst%32
#define CB_BITS 12
#define KEYS_PER_CB (1 << CB_BITS)                             // 4096
#define NCB  ((NBINS2 + KEYS_PER_CB - 1) >> CB_BITS)           // 245
#define EB   4096
#define SORT_BLOCKS ((N_EDGES + EB - 1) / EB)                  // 391

typedef __attribute__((ext_vector_type(8))) short bf16x8;
typedef __attribute__((ext_vector_type(4))) float f32x4;

static __device__ __forceinline__ unsigned short f2bf(float f) {
    union { float f; unsigned int u; } v; v.f = f;
    unsigned int r = (v.u + 0x7FFFu + ((v.u >> 16) & 1u)) >> 16;   // RNE
    return (unsigned short)r;
}
static __device__ __forceinline__ float bf2f(unsigned short s) {
    union { unsigned int u; float f; } v; v.u = ((unsigned int)s) << 16;
    return v.f;
}

// ---------- prep ----------
// WtF[r][o][k] = bf16( W_r[k][o] ) : per-rel contiguous 32 KB; r==20 -> selfW[o][k]
__global__ void compute_wt(const float* __restrict__ bases,
                           const float* __restrict__ bw,
                           const float* __restrict__ selfW,
                           unsigned short* __restrict__ WtF) {
    int t = blockIdx.x * blockDim.x + threadIdx.x;
    const int total = (N_REL + 1) * DIM * DIM;
    if (t >= total) return;
    int r = t >> 14;                      // /16384
    int rem = t & 16383;
    int o = rem >> 7;
    int k = rem & 127;
    float v;
    if (r < N_REL) {
        v = 0.f;
        #pragma unroll
        for (int bb = 0; bb < N_BASIS; ++bb)
            v += bw[r * N_BASIS + bb] * bases[((size_t)bb * DIM + k) * DIM + o];
    } else {
        v = selfW[o * DIM + k];
    }
    WtF[t] = f2bf(v);
}

__global__ void build_xb(const float* __restrict__ x, unsigned short* __restrict__ xb) {
    int t = blockIdx.x * blockDim.x + threadIdx.x;
    const int total = N_NODES * DIM;
    if (t < total) xb[t] = f2bf(x[t]);
}

__global__ void build_invn(const float* __restrict__ norm, float* __restrict__ invn) {
    int t = blockIdx.x * blockDim.x + threadIdx.x;
    const int total = N_REL * N_NODES;
    if (t < total) invn[t] = 1.0f / norm[t];
}

// ---------- two-level counting sort by key = (dst/32)*640 + r*32 + (dst%32) ----------
__global__ __launch_bounds__(256) void hist_coarse(const int* __restrict__ eidx,
                                                   const int* __restrict__ etype,
                                                   unsigned int* __restrict__ btot) {
    __shared__ unsigned int h[NCB];
    for (int i = threadIdx.x; i < NCB; i += 256) h[i] = 0;
    __syncthreads();
    int base = blockIdx.x * EB;
    #pragma unroll
    for (int k = 0; k < EB / 256; ++k) {
        int e = base + k * 256 + threadIdx.x;
        if (e < N_EDGES) {
            int dst = eidx[N_EDGES + e];
            int key = (dst >> 5) * KEYB + etype[e] * 32 + (dst & 31);
            atomicAdd(&h[key >> CB_BITS], 1u);
        }
    }
    __syncthreads();
    for (int i = threadIdx.x; i < NCB; i += 256)
        if (h[i]) atomicAdd(&btot[i], h[i]);
}

__global__ __launch_bounds__(256) void scan_coarse(const unsigned int* __restrict__ btot,
                                                   unsigned int* __restrict__ cbase,
                                                   unsigned int* __restrict__ ccur,
                                                   unsigned int* __restrict__ binstart) {
    __shared__ unsigned int lds[256];
    int t = threadIdx.x;
    unsigned int v = (t < NCB) ? btot[t] : 0u;
    lds[t] = v; __syncthreads();
    for (int off = 1; off < 256; off <<= 1) {
        unsigned int a = (t >= off) ? lds[t - off] : 0u;
        __syncthreads();
        lds[t] += a;
        __syncthreads();
    }
    unsigned int excl = lds[t] - v;
    if (t < NCB) { cbase[t] = excl; ccur[t] = excl; }
    if (t == NCB - 1) cbase[NCB] = lds[t];        // == N_EDGES
    if (t == 0) binstart[NBINS2] = N_EDGES;       // global sentinel
}

__global__ __launch_bounds__(256) void place_coarse(const int* __restrict__ eidx,
                                                    const int* __restrict__ etype,
                                                    unsigned int* __restrict__ ccur,
                                                    unsigned int* __restrict__ ebuf) {
    __shared__ unsigned int h[NCB];
    __shared__ unsigned int cur[NCB];
    for (int i = threadIdx.x; i < NCB; i += 256) h[i] = 0;
    __syncthreads();
    int base = blockIdx.x * EB;
    #pragma unroll
    for (int k = 0; k < EB / 256; ++k) {
        int e = base + k * 256 + threadIdx.x;
        if (e < N_EDGES) {
            int dst = eidx[N_EDGES + e];
            int key = (dst >> 5) * KEYB + etype[e] * 32 + (dst & 31);
            atomicAdd(&h[key >> CB_BITS], 1u);
        }
    }
    __syncthreads();
    for (int i = threadIdx.x; i < NCB; i += 256)
        cur[i] = atomicAdd(&ccur[i], h[i]);       // reserve private run
    __syncthreads();
    #pragma unroll
    for (int k = 0; k < EB / 256; ++k) {
        int e = base + k * 256 + threadIdx.x;
        if (e < N_EDGES) {
            unsigned int src = (unsigned int)eidx[e];
            int dst = eidx[N_EDGES + e];
            int key = (dst >> 5) * KEYB + etype[e] * 32 + (dst & 31);
            int cb = key >> CB_BITS;
            unsigned int klo = (unsigned int)(key & (KEYS_PER_CB - 1));
            unsigned int pos = atomicAdd(&cur[cb], 1u);
            ebuf[pos] = (klo << 16) | src;        // src < 65536
        }
    }
}

__global__ __launch_bounds__(256) void place_fine(const unsigned int* __restrict__ cbase,
                                                  const unsigned int* __restrict__ ebuf,
                                                  unsigned int* __restrict__ sorted,
                                                  unsigned int* __restrict__ binstart) {
    __shared__ unsigned int h[KEYS_PER_CB];
    __shared__ unsigned int cur[KEYS_PER_CB];
    __shared__ unsigned int pscan[256];
    int b = blockIdx.x, t = threadIdx.x;
    unsigned int s = cbase[b], e = cbase[b + 1];
    #pragma unroll
    for (int q = 0; q < 16; ++q) h[t * 16 + q] = 0;
    __syncthreads();
    for (unsigned int j = s + t; j < e; j += 256)
        atomicAdd(&h[ebuf[j] >> 16], 1u);
    __syncthreads();
    unsigned int c[16], part = 0;
    #pragma unroll
    for (int q = 0; q < 16; ++q) { c[q] = h[t * 16 + q]; part += c[q]; }
    pscan[t] = part; __syncthreads();
    for (int off = 1; off < 256; off <<= 1) {
        unsigned int a = (t >= off) ? pscan[t - off] : 0u;
        __syncthreads();
        pscan[t] += a;
        __syncthreads();
    }
    unsigned int run = pscan[t] - part;
    #pragma unroll
    for (int q = 0; q < 16; ++q) {
        int key = b * KEYS_PER_CB + t * 16 + q;
        if (key < NBINS2) binstart[key] = s + run;
        cur[t * 16 + q] = run;
        run += c[q];
    }
    __syncthreads();
    for (unsigned int j = s + t; j < e; j += 256) {
        unsigned int v = ebuf[j];
        unsigned int klo = v >> 16;
        unsigned int pos = s + atomicAdd(&cur[klo], 1u);
        sorted[pos] = ((klo & 31u) << 16) | (v & 0xFFFFu);   // payload: dloc | src
    }
}

// ---------- fused tile kernel: 32 dst/block, loop 21 rels: gather->LDS tile -> MFMA ----------
__global__ __launch_bounds__(256) void rgcn_tile(const unsigned short* __restrict__ WtF,
                                                 const unsigned int* __restrict__ xb32,
                                                 const unsigned int* __restrict__ sorted,
                                                 const unsigned int* __restrict__ binstart,
                                                 const float* __restrict__ invn,
                                                 float* __restrict__ out) {
    __shared__ __align__(16) float tile[32 * 128];   // 16 KB f32, swizzle: word ^= (row&7)<<2
    __shared__ float nlds[(N_REL + 1) * 32];         // 2.6 KB inv-norms (+1.0 for self)

    const int tid  = threadIdx.x;
    const int lane = tid & 63;
    const int wv   = tid >> 6;
    const int r16  = lane & 15;
    const int hi4  = lane >> 4;
    const int b    = blockIdx.x;
    const int nb   = b * 32;

    // block init: inv-norms (+self slot = 1.0)
    for (int q = tid; q < (N_REL + 1) * 32; q += 256) {
        int r = q >> 5, d = nb + (q & 31);
        nlds[q] = (r < N_REL && d < N_NODES) ? invn[(size_t)r * N_NODES + d] : 1.0f;
    }
    // per-wave: 21 segment boundaries (lane l -> binstart of rel l's first bin)
    unsigned int bound = (lane <= N_REL) ? binstart[(size_t)b * KEYB + lane * 32] : 0u;

    f32x4 acc[2][2];
    #pragma unroll
    for (int g = 0; g < 2; ++g)
        #pragma unroll
        for (int of = 0; of < 2; ++of) acc[g][of] = (f32x4){0.f, 0.f, 0.f, 0.f};

    for (int r = 0; r <= N_REL; ++r) {
        __syncthreads();                              // tile WAR (and nlds ready at r=0)
        #pragma unroll
        for (int q = 0; q < 4; ++q)                   // zero 32x128 f32
            *(f32x4*)&tile[(q * 256 + tid) * 4] = (f32x4){0.f, 0.f, 0.f, 0.f};
        __syncthreads();

        if (r < N_REL) {
            unsigned int rs = __shfl(bound, r), re = __shfl(bound, r + 1);
            unsigned int seg = re - rs;
            unsigned int Q = (seg + 3) >> 2;
            unsigned int start = rs + (unsigned int)wv * Q; if (start > re) start = re;
            unsigned int end = start + Q; if (end > re) end = re;

            #define EDGE(E, W) do {                                              \
                int dl_ = (int)((E) >> 16);                                      \
                int sw_ = (dl_ & 7) << 2;                                        \
                atomicAdd(&tile[dl_ * 128 + ((2 * lane)     ^ sw_)],             \
                          bf2f((unsigned short)((W) & 0xFFFF)));                 \
                atomicAdd(&tile[dl_ * 128 + ((2 * lane + 1) ^ sw_)],             \
                          bf2f((unsigned short)((W) >> 16)));                    \
            } while (0)

            for (unsigned int jj = start; jj < end; jj += 64) {
                unsigned int rem = end - jj;
                int chunk = (rem < 64u) ? (int)rem : 64;
                unsigned int ent = (lane < chunk) ? sorted[jj + lane] : 0u;
                int u = 0;
                for (; u + 8 <= chunk; u += 8) {      // 8 row-gathers in flight
                    unsigned int e0 = __shfl(ent, u),     e1 = __shfl(ent, u + 1);
                    unsigned int e2 = __shfl(ent, u + 2), e3 = __shfl(ent, u + 3);
                    unsigned int e4 = __shfl(ent, u + 4), e5 = __shfl(ent, u + 5);
                    unsigned int e6 = __shfl(ent, u + 6), e7 = __shfl(ent, u + 7);
                    unsigned int w0 = xb32[(size_t)(e0 & 0xFFFF) * 64 + lane];
                    unsigned int w1 = xb32[(size_t)(e1 & 0xFFFF) * 64 + lane];
                    unsigned int w2 = xb32[(size_t)(e2 & 0xFFFF) * 64 + lane];
                    unsigned int w3 = xb32[(size_t)(e3 & 0xFFFF) * 64 + lane];
                    unsigned int w4 = xb32[(size_t)(e4 & 0xFFFF) * 64 + lane];
                    unsigned int w5 = xb32[(size_t)(e5 & 0xFFFF) * 64 + lane];
                    unsigned int w6 = xb32[(size_t)(e6 & 0xFFFF) * 64 + lane];
                    unsigned int w7 = xb32[(size_t)(e7 & 0xFFFF) * 64 + lane];
                    EDGE(e0, w0); EDGE(e1, w1); EDGE(e2, w2); EDGE(e3, w3);
                    EDGE(e4, w4); EDGE(e5, w5); EDGE(e6, w6); EDGE(e7, w7);
                }
                for (; u < chunk; ++u) {
                    unsigned int e = __shfl(ent, u);
                    unsigned int w = xb32[(size_t)(e & 0xFFFF) * 64 + lane];
                    EDGE(e, w);
                }
            }
            #undef EDGE
        } else {                                      // self loop: tile = xb rows (norm=1)
            #pragma unroll
            for (int q = 0; q < 8; ++q) {
                int idx = q * 256 + tid;              // 2048 u32
                int row = idx >> 6, c = idx & 63;
                int gn = nb + row;
                unsigned int w = (gn < N_NODES) ? xb32[(size_t)gn * 64 + c] : 0u;
                int sw = (row & 7) << 2;
                tile[row * 128 + ((2 * c)     ^ sw)] = bf2f((unsigned short)(w & 0xFFFF));
                tile[row * 128 + ((2 * c + 1) ^ sw)] = bf2f((unsigned short)(w >> 16));
            }
        }
        __syncthreads();

        // Phase B: norm-scaled tile -> bf16 frags, W frags straight from L2, 16 MFMA/wave
        const unsigned short* Wr = WtF + (size_t)r * (DIM * DIM);
        float nl0 = nlds[r * 32 + r16];
        float nl1 = nlds[r * 32 + 16 + r16];
        #pragma unroll
        for (int ks = 0; ks < 4; ++ks) {
            int kb = ks * 32 + hi4 * 8;
            bf16x8 bfr[2];
            #pragma unroll
            for (int g = 0; g < 2; ++g) {
                int n = g * 16 + r16;
                int sw = (n & 7) << 2;
                float s = g ? nl1 : nl0;
                f32x4 a = *(const f32x4*)&tile[n * 128 + ( kb      ^ sw)];
                f32x4 c = *(const f32x4*)&tile[n * 128 + ((kb + 4) ^ sw)];
                unsigned int p0, p1, p2, p3;
                asm("v_cvt_pk_bf16_f32 %0, %1, %2" : "=v"(p0) : "v"(a.x * s), "v"(a.y * s));
                asm("v_cvt_pk_bf16_f32 %0, %1, %2" : "=v"(p1) : "v"(a.z * s), "v"(a.w * s));
                asm("v_cvt_pk_bf16_f32 %0, %1, %2" : "=v"(p2) : "v"(c.x * s), "v"(c.y * s));
                asm("v_cvt_pk_bf16_f32 %0, %1, %2" : "=v"(p3) : "v"(c.z * s), "v"(c.w * s));
                union { unsigned int w4[4]; bf16x8 v; } uu;
                uu.w4[0] = p0; uu.w4[1] = p1; uu.w4[2] = p2; uu.w4[3] = p3;
                bfr[g] = uu.v;
            }
            #pragma unroll
            for (int of = 0; of < 2; ++of) {
                int o = wv * 32 + of * 16 + r16;
                bf16x8 afr = *(const bf16x8*)&Wr[o * 128 + ks * 32 + hi4 * 8];
                acc[0][of] = __builtin_amdgcn_mfma_f32_16x16x32_bf16(afr, bfr[0], acc[0][of], 0, 0, 0);
                acc[1][of] = __builtin_amdgcn_mfma_f32_16x16x32_bf16(afr, bfr[1], acc[1][of], 0, 0, 0);
            }
        }
    }

    // epilogue: D col = r16 -> n, row = hi4*4+reg -> o; each wave owns 32 o-columns
    #pragma unroll
    for (int g = 0; g < 2; ++g) {
        int n = nb + g * 16 + r16;
        if (n < N_NODES) {
            #pragma unroll
            for (int of = 0; of < 2; ++of) {
                f32x4 v = acc[g][of];
                *(float4*)(out + (size_t)n * DIM + wv * 32 + of * 16 + hi4 * 4) =
                    (float4){v.x, v.y, v.z, v.w};
            }
        }
    }
}

extern "C" void kernel_launch(void* const* d_in, const int* in_sizes, int n_in,
                              void* d_out, int out_size, void* d_ws, size_t ws_size,
                              hipStream_t stream) {
    const float* x     = (const float*)d_in[0];
    const int*   eidx  = (const int*)d_in[1];
    const int*   etype = (const int*)d_in[2];
    const float* norm  = (const float*)d_in[3];
    const float* selfW = (const float*)d_in[4];
    const float* bases = (const float*)d_in[5];
    const float* bw    = (const float*)d_in[6];
    float* out = (float*)d_out;

    // ---- workspace (~35 MB) ----
    char* p = (char*)d_ws;
    auto alloc = [&](size_t bytes) { char* q = p; p += (bytes + 255) & ~(size_t)255; return q; };
    unsigned short* WtF      = (unsigned short*)alloc((size_t)(N_REL + 1) * DIM * DIM * 2); // 0.69 MB
    unsigned short* xb       = (unsigned short*)alloc((size_t)N_NODES * DIM * 2);           // 12.8 MB
    float*          invn     = (float*)alloc((size_t)N_REL * N_NODES * 4);                  // 4.0 MB
    unsigned int*   sorted   = (unsigned int*)alloc((size_t)N_EDGES * 4);                   // 6.4 MB
    unsigned int*   binstart = (unsigned int*)alloc((size_t)(NBINS2 + 1) * 4);              // 4.0 MB
    unsigned int*   ebuf     = (unsigned int*)alloc((size_t)N_EDGES * 4);                   // 6.4 MB
    unsigned int*   btot     = (unsigned int*)alloc((size_t)NCB * 4);
    unsigned int*   cbase    = (unsigned int*)alloc((size_t)(NCB + 1) * 4);
    unsigned int*   ccur     = (unsigned int*)alloc((size_t)NCB * 4);
    (void)ws_size;

    // 1. prep
    {
        int total = (N_REL + 1) * DIM * DIM;
        compute_wt<<<dim3((total + 255) / 256), dim3(256), 0, stream>>>(bases, bw, selfW, WtF);
        total = N_NODES * DIM;
        build_xb<<<dim3((total + 255) / 256), dim3(256), 0, stream>>>(x, xb);
        total = N_REL * N_NODES;
        build_invn<<<dim3((total + 255) / 256), dim3(256), 0, stream>>>(norm, invn);
    }

    // 2. two-level counting sort by key = (dst/32)*640 + r*32 + dst%32
    hipMemsetAsync(btot, 0, (size_t)NCB * 4, stream);
    hist_coarse<<<dim3(SORT_BLOCKS), dim3(256), 0, stream>>>(eidx, etype, btot);
    scan_coarse<<<dim3(1), dim3(256), 0, stream>>>(btot, cbase, ccur, binstart);
    place_coarse<<<dim3(SORT_BLOCKS), dim3(256), 0, stream>>>(eidx, etype, ccur, ebuf);
    place_fine<<<dim3(NCB), dim3(256), 0, stream>>>(cbase, ebuf, sorted, binstart);

    // 3. fused tile kernel: gather + GEMM + self-loop, out written once, no agg buffer
    rgcn_tile<<<dim3(NBLK), dim3(256), 0, stream>>>(
        WtF, (const unsigned int*)xb, sorted, binstart, invn, out);
}

// Round 14
// 296.798 us; speedup vs baseline: 4.6770x; 4.6770x over previous
//
#include <hip/hip_runtime.h>
#include <hip/hip_bf16.h>

#define N_NODES 50000
#define N_EDGES 1600000
#define N_REL   20
#define N_BASIS 16
#define DIM     128
#define KTOT    ((N_REL + 1) * DIM)      // 2688 : Wt row stride (20 rels + self)

#define NBINS   (N_NODES * N_REL)        // 1,000,000 : key = dst*20 + r  (dst-major)
#define CB_BITS 12
#define KEYS_PER_CB (1 << CB_BITS)                            // 4096
#define NCB  ((NBINS + KEYS_PER_CB - 1) >> CB_BITS)           // 245
#define CAP  8192                                             // slack bucket capacity (exp 6554)
#define EB   4096
#define SORT_BLOCKS ((N_EDGES + EB - 1) / EB)                 // 391
#define BKG  64                                               // GEMM K-tile

typedef __attribute__((ext_vector_type(8))) short          bf16x8;
typedef __attribute__((ext_vector_type(4))) float          f32x4;

static __device__ __forceinline__ unsigned short f2bf(float f) {
    union { float f; unsigned int u; } v; v.f = f;
    unsigned int r = (v.u + 0x7FFFu + ((v.u >> 16) & 1u)) >> 16;   // RNE
    return (unsigned short)r;
}
static __device__ __forceinline__ float bf2f(unsigned short s) {
    union { unsigned int u; float f; } v; v.u = ((unsigned int)s) << 16;
    return v.f;
}

// ---------- prep (also zero-inits sort cursors: runs before place_slack in-stream) ----------
__global__ void compute_wt(const float* __restrict__ bases,
                           const float* __restrict__ bw,
                           const float* __restrict__ selfW,
                           unsigned short* __restrict__ Wt,
                           unsigned int* __restrict__ ccur) {
    int t = blockIdx.x * blockDim.x + threadIdx.x;
    if (blockIdx.x == 0 && threadIdx.x < NCB) ccur[threadIdx.x] = 0;
    const int total = DIM * (N_REL + 1) * DIM;
    if (t >= total) return;
    int i = t & (DIM - 1);
    int r = (t >> 7) % (N_REL + 1);
    int o = t / (DIM * (N_REL + 1));
    float v;
    if (r < N_REL) {
        v = 0.f;
        #pragma unroll
        for (int b = 0; b < N_BASIS; ++b)
            v += bw[r * N_BASIS + b] * bases[((size_t)b * DIM + i) * DIM + o];
    } else {
        v = selfW[o * DIM + i];
    }
    Wt[(size_t)o * KTOT + r * DIM + i] = f2bf(v);
}

__global__ void build_xb(const float* __restrict__ x, unsigned short* __restrict__ xb) {
    int t = blockIdx.x * blockDim.x + threadIdx.x;
    const int total = N_NODES * DIM;
    if (t < total) xb[t] = f2bf(x[t]);
}

// normT[d*20+r] = 1/norm[r*N+d]
__global__ __launch_bounds__(256) void build_normT(const float* __restrict__ norm,
                                                   float* __restrict__ normT) {
    __shared__ float tile[64][21];
    int d0 = blockIdx.x * 64;
    int t = threadIdx.x;
    #pragma unroll
    for (int q = 0; q < 5; ++q) {
        int idx = q * 256 + t;                 // 1280 = 20 r x 64 d
        int r = idx >> 6, dc = idx & 63;
        if (r < N_REL && d0 + dc < N_NODES)
            tile[dc][r] = 1.0f / norm[(size_t)r * N_NODES + d0 + dc];
    }
    __syncthreads();
    #pragma unroll
    for (int q = 0; q < 5; ++q) {
        int idx = q * 256 + t;
        int d = idx / 20, r = idx - d * 20;
        if (idx < 1280 && d0 + d < N_NODES)
            normT[(size_t)(d0 + d) * 20 + r] = tile[d][r];
    }
}

// ---------- single-pass slack sort by key = dst*20 + r ----------
// place_slack: per-block LDS hist -> reserve private runs in slack bucket (base = cb*CAP)
__global__ __launch_bounds__(256) void place_slack(const int* __restrict__ eidx,
                                                   const int* __restrict__ etype,
                                                   unsigned int* __restrict__ ccur,
                                                   unsigned int* __restrict__ ebuf) {
    __shared__ unsigned int h[NCB];
    __shared__ unsigned int cur[NCB];
    for (int i = threadIdx.x; i < NCB; i += 256) h[i] = 0;
    __syncthreads();
    int base = blockIdx.x * EB;
    #pragma unroll
    for (int k = 0; k < EB / 256; ++k) {
        int e = base + k * 256 + threadIdx.x;
        if (e < N_EDGES) {
            int key = eidx[N_EDGES + e] * N_REL + etype[e];
            atomicAdd(&h[key >> CB_BITS], 1u);
        }
    }
    __syncthreads();
    for (int i = threadIdx.x; i < NCB; i += 256)
        cur[i] = atomicAdd(&ccur[i], h[i]);       // reserve private run (cursor from 0)
    __syncthreads();
    #pragma unroll
    for (int k = 0; k < EB / 256; ++k) {
        int e = base + k * 256 + threadIdx.x;
        if (e < N_EDGES) {
            unsigned int src = (unsigned int)eidx[e];
            int key = eidx[N_EDGES + e] * N_REL + etype[e];
            int cb = key >> CB_BITS;
            unsigned int klo = (unsigned int)(key & (KEYS_PER_CB - 1));
            unsigned int pos = atomicAdd(&cur[cb], 1u);
            ebuf[(size_t)cb * CAP + pos] = (klo << 16) | src;   // src < 65536
        }
    }
}

// scan_fills: exclusive-scan the 245 bucket fills -> dense bases
__global__ __launch_bounds__(256) void scan_fills(const unsigned int* __restrict__ ccur,
                                                  unsigned int* __restrict__ cbase,
                                                  unsigned int* __restrict__ binstart) {
    __shared__ unsigned int lds[256];
    int t = threadIdx.x;
    unsigned int v = (t < NCB) ? ccur[t] : 0u;
    lds[t] = v; __syncthreads();
    for (int off = 1; off < 256; off <<= 1) {
        unsigned int a = (t >= off) ? lds[t - off] : 0u;
        __syncthreads();
        lds[t] += a;
        __syncthreads();
    }
    unsigned int excl = lds[t] - v;
    if (t < NCB) cbase[t] = excl;
    if (t == NCB - 1) cbase[NCB] = lds[t];        // == N_EDGES
    if (t == 0) binstart[NBINS] = N_EDGES;        // global sentinel
}

__global__ __launch_bounds__(256) void place_fine(const unsigned int* __restrict__ cbase,
                                                  const unsigned int* __restrict__ ccur,
                                                  const unsigned int* __restrict__ ebuf,
                                                  unsigned int* __restrict__ sorted,
                                                  unsigned int* __restrict__ binstart) {
    __shared__ unsigned int h[KEYS_PER_CB];
    __shared__ unsigned int cur[KEYS_PER_CB];
    __shared__ unsigned int pscan[256];
    int b = blockIdx.x, t = threadIdx.x;
    unsigned int fill = ccur[b];
    unsigned int s = cbase[b];                    // dense base in sorted
    const unsigned int* src = ebuf + (size_t)b * CAP;
    #pragma unroll
    for (int q = 0; q < 16; ++q) h[t * 16 + q] = 0;
    __syncthreads();
    for (unsigned int j = t; j < fill; j += 256)
        atomicAdd(&h[src[j] >> 16], 1u);
    __syncthreads();
    unsigned int c[16], part = 0;
    #pragma unroll
    for (int q = 0; q < 16; ++q) { c[q] = h[t * 16 + q]; part += c[q]; }
    pscan[t] = part; __syncthreads();
    for (int off = 1; off < 256; off <<= 1) {
        unsigned int a = (t >= off) ? pscan[t - off] : 0u;
        __syncthreads();
        pscan[t] += a;
        __syncthreads();
    }
    unsigned int run = pscan[t] - part;
    #pragma unroll
    for (int q = 0; q < 16; ++q) {
        int key = b * KEYS_PER_CB + t * 16 + q;
        if (key < NBINS) binstart[key] = s + run;
        cur[t * 16 + q] = run;
        run += c[q];
    }
    __syncthreads();
    for (unsigned int j = t; j < fill; j += 256) {
        unsigned int v = src[j];
        unsigned int klo = v >> 16;
        unsigned int key = (unsigned int)b * KEYS_PER_CB + klo;
        unsigned int r = key % N_REL;             // rel from key (magic-mul div)
        unsigned int pos = s + atomicAdd(&cur[klo], 1u);
        sorted[pos] = (r << 16) | (v & 0xFFFFu);  // payload: rel | src
    }
}

// ---------- reduce: wave per dst, register-resident edge stream, 8-wide load pipeline ----------
__global__ __launch_bounds__(256) void reduce_all(const unsigned int* __restrict__ sorted,
                                                  const unsigned int* __restrict__ binstart,
                                                  const unsigned int* __restrict__ xb32,
                                                  const float* __restrict__ normT,
                                                  unsigned int* __restrict__ agg32,
                                                  int r0, int rch, int rowK2) {
    int wv = threadIdx.x >> 6, lane = threadIdx.x & 63;
    int dst = blockIdx.x * 4 + wv;
    if (dst >= N_NODES) return;
    unsigned int nbase = (unsigned int)dst * N_REL;
    int rE  = r0 + rch;                          // exclusive end (may include slot 20 = self)
    int rEe = (rE < N_REL) ? rE : N_REL;         // exclusive end of edge-rels

    float nrm = (lane < rEe - r0) ? normT[nbase + r0 + lane] : 0.f;
    unsigned int bs = binstart[nbase + r0];
    unsigned int be = binstart[nbase + rEe];

    int cur_r = r0;
    float a0 = 0.f, a1 = 0.f;
    unsigned int pk, zz;
    asm("v_cvt_pk_bf16_f32 %0, %1, %2" : "=v"(zz) : "v"(0.f), "v"(0.f));

    #define FLUSH_ROW(RR, PKV) \
        agg32[(size_t)dst * rowK2 + ((RR) - r0) * 64 + lane] = (PKV)

    #define PROCESS(E, W) do {                                               \
        int rr_ = (int)((E) >> 16);                                          \
        if (rr_ != cur_r) {                                                  \
            float inv_ = __shfl(nrm, cur_r - r0);                            \
            float s0_ = a0 * inv_, s1_ = a1 * inv_;                          \
            asm("v_cvt_pk_bf16_f32 %0, %1, %2" : "=v"(pk) : "v"(s0_), "v"(s1_)); \
            FLUSH_ROW(cur_r, pk);                                            \
            for (int z_ = cur_r + 1; z_ < rr_; ++z_) FLUSH_ROW(z_, zz);      \
            a0 = 0.f; a1 = 0.f; cur_r = rr_;                                 \
        }                                                                    \
        a0 += bf2f((unsigned short)((W) & 0xFFFF));                          \
        a1 += bf2f((unsigned short)((W) >> 16));                             \
    } while (0)

    for (unsigned int j = bs; j < be; ) {
        unsigned int rem = be - j;
        int chunk = (rem < 64u) ? (int)rem : 64;
        unsigned int ent = (lane < chunk) ? sorted[j + lane] : 0u;  // wave-wide metadata load
        int u = 0;
        for (; u + 8 <= chunk; u += 8) {         // 8 independent gathers in flight
            unsigned int e0 = __shfl(ent, u),     e1 = __shfl(ent, u + 1);
            unsigned int e2 = __shfl(ent, u + 2), e3 = __shfl(ent, u + 3);
            unsigned int e4 = __shfl(ent, u + 4), e5 = __shfl(ent, u + 5);
            unsigned int e6 = __shfl(ent, u + 6), e7 = __shfl(ent, u + 7);
            unsigned int w0 = xb32[(size_t)(e0 & 0xFFFF) * 64 + lane];
            unsigned int w1 = xb32[(size_t)(e1 & 0xFFFF) * 64 + lane];
            unsigned int w2 = xb32[(size_t)(e2 & 0xFFFF) * 64 + lane];
            unsigned int w3 = xb32[(size_t)(e3 & 0xFFFF) * 64 + lane];
            unsigned int w4 = xb32[(size_t)(e4 & 0xFFFF) * 64 + lane];
            unsigned int w5 = xb32[(size_t)(e5 & 0xFFFF) * 64 + lane];
            unsigned int w6 = xb32[(size_t)(e6 & 0xFFFF) * 64 + lane];
            unsigned int w7 = xb32[(size_t)(e7 & 0xFFFF) * 64 + lane];
            PROCESS(e0, w0); PROCESS(e1, w1); PROCESS(e2, w2); PROCESS(e3, w3);
            PROCESS(e4, w4); PROCESS(e5, w5); PROCESS(e6, w6); PROCESS(e7, w7);
        }
        for (; u < chunk; ++u) {
            unsigned int e = __shfl(ent, u);
            unsigned int w = xb32[(size_t)(e & 0xFFFF) * 64 + lane];
            PROCESS(e, w);
        }
        j += chunk;
    }
    {
        float inv = __shfl(nrm, cur_r - r0);
        float s0 = a0 * inv, s1 = a1 * inv;
        asm("v_cvt_pk_bf16_f32 %0, %1, %2" : "=v"(pk) : "v"(s0), "v"(s1));
        FLUSH_ROW(cur_r, pk);
        for (int z = cur_r + 1; z < rEe; ++z) FLUSH_ROW(z, zz);
    }
    if (rE > N_REL) {                            // self-loop slot (virtual rel 20)
        unsigned int w = xb32[(size_t)dst * 64 + lane];
        float s0 = bf2f((unsigned short)(w & 0xFFFF));
        float s1 = bf2f((unsigned short)(w >> 16));
        asm("v_cvt_pk_bf16_f32 %0, %1, %2" : "=v"(pk) : "v"(s0), "v"(s1));
        agg32[(size_t)dst * rowK2 + (N_REL - r0) * 64 + lane] = pk;
    }
    #undef PROCESS
    #undef FLUSH_ROW
}

// ---------- MFMA GEMM: dbuf global_load_lds, counted vmcnt(6) before compute ----------
// out[n][o] (+)= sum_k Wt_sub[o*KTOT+k] * Bsrc[n*K+k].  Tile: 64 n x 128 o, BK=64.
// LDS rows = 64 shorts (128 B); chunk slot kq holds global chunk kq ^ (row&7).
__global__ __launch_bounds__(256) void gemm_bf(const unsigned short* __restrict__ Wt_sub,
                                               const unsigned short* __restrict__ Bsrc,
                                               int K,
                                               float* __restrict__ C,
                                               int acc_mode) {
    __shared__ __align__(16) unsigned short WsL[2][128 * BKG];   // 32 KB
    __shared__ __align__(16) unsigned short AsL[2][64 * BKG];    // 16 KB

    const int tid  = threadIdx.x;
    const int lane = tid & 63;
    const int wv   = tid >> 6;
    const int wo   = wv >> 1;                    // o-half (0..1): 64 o rows
    const int wn   = wv & 1;                     // n-half (0..1): 32 n rows
    const int r16  = lane & 15;
    const int hi4  = lane >> 4;
    const int nb   = blockIdx.x * 64;

    // staging: per issue, each wave fills 8 rows (lane>>3 = row-in-group, lane&7 = 16B chunk)
    const int srow = lane >> 3;
    const int kq   = lane & 7;
    const unsigned short* sW[4];
    #pragma unroll
    for (int i = 0; i < 4; ++i) {
        int row = wv * 8 + srow + i * 32;
        sW[i] = Wt_sub + (size_t)row * KTOT + ((kq * 8) ^ ((row & 7) << 3));
    }
    const unsigned short* sA[2];
    #pragma unroll
    for (int j = 0; j < 2; ++j) {
        int row = wv * 8 + srow + j * 32;
        int gn = nb + row; if (gn >= N_NODES) gn = N_NODES - 1;   // clamp (dup rows unused)
        sA[j] = Bsrc + (size_t)gn * K + ((kq * 8) ^ ((row & 7) << 3));
    }

    #define GL16(SRC, DST) __builtin_amdgcn_global_load_lds( \
        (const __attribute__((address_space(1))) void*)(SRC), \
        (__attribute__((address_space(3))) void*)(DST), 16, 0, 0)

    #define STAGE(B) do {                                                  \
        _Pragma("unroll") for (int i_ = 0; i_ < 4; ++i_)                   \
            GL16(sW[i_], &WsL[B][(wv * 8 + i_ * 32) * BKG]);               \
        _Pragma("unroll") for (int j_ = 0; j_ < 2; ++j_)                   \
            GL16(sA[j_], &AsL[B][(wv * 8 + j_ * 32) * BKG]);               \
        _Pragma("unroll") for (int i_ = 0; i_ < 4; ++i_) sW[i_] += BKG;    \
        _Pragma("unroll") for (int j_ = 0; j_ < 2; ++j_) sA[j_] += BKG;    \
    } while (0)

    f32x4 acc[2][4];
    #pragma unroll
    for (int g = 0; g < 2; ++g)
        #pragma unroll
        for (int of = 0; of < 4; ++of) acc[g][of] = (f32x4){0.f, 0.f, 0.f, 0.f};

    const int NT = K / BKG;
    STAGE(0);                                    // tile 0 in flight

    int cur = 0;
    for (int t = 0; t < NT; ++t) {
        if (t + 1 < NT) {
            STAGE(cur ^ 1);                      // issue tile t+1 (6 loads; stay in flight)
            asm volatile("s_waitcnt vmcnt(6)" ::: "memory");   // tile t landed; t+1 pending
        } else {
            asm volatile("s_waitcnt vmcnt(0)" ::: "memory");
        }
        __builtin_amdgcn_s_barrier();            // all waves' tile-t DMA visible
        __builtin_amdgcn_sched_barrier(0);

        const unsigned short* Wb = WsL[cur];
        const unsigned short* Ab = AsL[cur];
        #pragma unroll
        for (int ks = 0; ks < 2; ++ks) {
            int g = ks * 4 + hi4;                // global 16B-chunk index (k = g*8)
            bf16x8 bfr[2];
            #pragma unroll
            for (int q = 0; q < 2; ++q) {
                int nr = wn * 32 + q * 16 + r16;
                bfr[q] = *(const bf16x8*)&Ab[nr * BKG + ((g ^ (nr & 7)) << 3)];
            }
            #pragma unroll
            for (int of = 0; of < 4; ++of) {
                int ro = wo * 64 + of * 16 + r16;
                bf16x8 afr = *(const bf16x8*)&Wb[ro * BKG + ((g ^ (ro & 7)) << 3)];
                acc[0][of] = __builtin_amdgcn_mfma_f32_16x16x32_bf16(afr, bfr[0], acc[0][of], 0, 0, 0);
                acc[1][of] = __builtin_amdgcn_mfma_f32_16x16x32_bf16(afr, bfr[1], acc[1][of], 0, 0, 0);
            }
        }
        __builtin_amdgcn_sched_barrier(0);
        __builtin_amdgcn_s_barrier();            // reads of buf[cur] done before next STAGE(cur)
        cur ^= 1;
    }
    #undef STAGE
    #undef GL16

    // epilogue: D col = r16 -> n, row = hi4*4+reg -> o (within frag)
    #pragma unroll
    for (int g = 0; g < 2; ++g) {
        int n = nb + wn * 32 + g * 16 + r16;
        if (n < N_NODES) {
            #pragma unroll
            for (int of = 0; of < 4; ++of) {
                float* p = C + (size_t)n * DIM + wo * 64 + of * 16 + hi4 * 4;
                if (acc_mode) {
                    p[0] += acc[g][of].x; p[1] += acc[g][of].y;
                    p[2] += acc[g][of].z; p[3] += acc[g][of].w;
                } else {
                    f32x4 v = acc[g][of];
                    *(float4*)p = (float4){v.x, v.y, v.z, v.w};
                }
            }
        }
    }
}

extern "C" void kernel_launch(void* const* d_in, const int* in_sizes, int n_in,
                              void* d_out, int out_size, void* d_ws, size_t ws_size,
                              hipStream_t stream) {
    const float* x     = (const float*)d_in[0];
    const int*   eidx  = (const int*)d_in[1];
    const int*   etype = (const int*)d_in[2];
    const float* norm  = (const float*)d_in[3];
    const float* selfW = (const float*)d_in[4];
    const float* bases = (const float*)d_in[5];
    const float* bw    = (const float*)d_in[6];
    float* out = (float*)d_out;

    // ---- workspace: fixed ~37 MB, agg takes the rest (chunked) ----
    char* p = (char*)d_ws;
    auto alloc = [&](size_t bytes) { char* q = p; p += (bytes + 255) & ~(size_t)255; return q; };
    unsigned short* Wt       = (unsigned short*)alloc((size_t)DIM * KTOT * 2);   // 0.69 MB
    unsigned short* xb       = (unsigned short*)alloc((size_t)N_NODES * DIM * 2);// 12.8 MB
    float*          normT    = (float*)alloc((size_t)N_NODES * N_REL * 4);       // 4.0 MB
    unsigned int*   sorted   = (unsigned int*)alloc((size_t)N_EDGES * 4);        // 6.4 MB
    unsigned int*   binstart = (unsigned int*)alloc((size_t)(NBINS + 1) * 4);    // 4.0 MB
    unsigned int*   ebuf     = (unsigned int*)alloc((size_t)NCB * CAP * 4);      // 8.0 MB slack
    unsigned int*   cbase    = (unsigned int*)alloc((size_t)(NCB + 1) * 4);
    unsigned int*   ccur     = (unsigned int*)alloc((size_t)NCB * 4);
    unsigned int*   agg32    = (unsigned int*)p;                                 // rest
    size_t fixed = (size_t)(p - (char*)d_ws);
    size_t per_rel = (size_t)N_NODES * DIM * 2;                                  // 12.8 MB
    // rch=7: agg chunk = 89.6 MB -> L3-resident producer->consumer handoff
    int rch = 7;
    {
        size_t avail = (ws_size > fixed) ? ws_size - fixed : 0;
        int m = (int)(avail / per_rel);
        if (m < rch) rch = m;
        if (rch < 1) rch = 1;
    }

    // 1. prep (compute_wt also zero-inits ccur ahead of place_slack)
    {
        int total = DIM * (N_REL + 1) * DIM;
        compute_wt<<<dim3((total + 255) / 256), dim3(256), 0, stream>>>(bases, bw, selfW, Wt, ccur);
        total = N_NODES * DIM;
        build_xb<<<dim3((total + 255) / 256), dim3(256), 0, stream>>>(x, xb);
        build_normT<<<dim3((N_NODES + 63) / 64), dim3(256), 0, stream>>>(norm, normT);
    }

    // 2. single-pass slack sort by key = dst*20 + r
    place_slack<<<dim3(SORT_BLOCKS), dim3(256), 0, stream>>>(eidx, etype, ccur, ebuf);
    scan_fills<<<dim3(1), dim3(256), 0, stream>>>(ccur, cbase, binstart);
    place_fine<<<dim3(NCB), dim3(256), 0, stream>>>(cbase, ccur, ebuf, sorted, binstart);

    // 3. per chunk of rch rels (21 virtual rels incl. self): reduce + GEMM (L3-hot handoff)
    int gblocks = (N_NODES + 63) / 64;
    for (int r0 = 0; r0 < N_REL + 1; r0 += rch) {
        int rchA = (rch < N_REL + 1 - r0) ? rch : (N_REL + 1 - r0);
        reduce_all<<<dim3((N_NODES + 3) / 4), dim3(256), 0, stream>>>(
            sorted, binstart, (const unsigned int*)xb, normT, agg32, r0, rchA, rchA * 64);
        gemm_bf<<<dim3(gblocks), dim3(256), 0, stream>>>(
            Wt + r0 * DIM, (const unsigned short*)agg32, rchA * DIM, out, r0 > 0);
    }
}

// Round 15
// 277.346 us; speedup vs baseline: 5.0050x; 1.0701x over previous
//
#include <hip/hip_runtime.h>
#include <hip/hip_bf16.h>

#define N_NODES 50000
#define N_EDGES 1600000
#define N_REL   20
#define N_BASIS 16
#define DIM     128
#define KTOT    ((N_REL + 1) * DIM)      // 2688 : Wt row stride (20 rels + self)

#define NBINS   (N_NODES * N_REL)        // 1,000,000 : key = dst*20 + r  (dst-major)
#define CB_BITS 12
#define KEYS_PER_CB (1 << CB_BITS)                            // 4096
#define NCB  ((NBINS + KEYS_PER_CB - 1) >> CB_BITS)           // 245
#define CAP  8192                                             // slack bucket capacity (exp 6554)
#define EB   4096
#define SORT_BLOCKS ((N_EDGES + EB - 1) / EB)                 // 391
#define BKG  32                                               // GEMM K-tile (24 KB LDS dbuf)

// prep_place block-range bases
#define WT_TOTAL  (DIM * (N_REL + 1) * DIM)                   // 344064
#define WT_BLOCKS (WT_TOTAL / 256)                            // 1344
#define XB_BLOCKS (N_NODES * DIM / 8 / 256)                   // 3125
#define NT_BLOCKS ((N_NODES + 63) / 64)                       // 782
#define WT_BASE   SORT_BLOCKS
#define XB_BASE   (WT_BASE + WT_BLOCKS)
#define NT_BASE   (XB_BASE + XB_BLOCKS)
#define PP_GRID   (NT_BASE + NT_BLOCKS)                       // 5642

typedef __attribute__((ext_vector_type(8))) short          bf16x8;
typedef __attribute__((ext_vector_type(4))) float          f32x4;
typedef __attribute__((ext_vector_type(8))) unsigned short ushort8v;

static __device__ __forceinline__ unsigned short f2bf(float f) {
    union { float f; unsigned int u; } v; v.f = f;
    unsigned int r = (v.u + 0x7FFFu + ((v.u >> 16) & 1u)) >> 16;   // RNE
    return (unsigned short)r;
}
static __device__ __forceinline__ float bf2f(unsigned short s) {
    union { unsigned int u; float f; } v; v.u = ((unsigned int)s) << 16;
    return v.f;
}

// ---------- merged prep + slack-place (independent work, one dispatch) ----------
__global__ __launch_bounds__(256) void prep_place(const float* __restrict__ x,
                                                  const int* __restrict__ eidx,
                                                  const int* __restrict__ etype,
                                                  const float* __restrict__ bases,
                                                  const float* __restrict__ bw,
                                                  const float* __restrict__ selfW,
                                                  const float* __restrict__ norm,
                                                  unsigned short* __restrict__ Wt,
                                                  unsigned short* __restrict__ xb,
                                                  float* __restrict__ normT,
                                                  unsigned int* __restrict__ ccur,
                                                  unsigned int* __restrict__ ebuf) {
    __shared__ unsigned int h[NCB];
    __shared__ unsigned int cur[NCB];
    __shared__ float tile[64][21];
    const int blk = blockIdx.x, tid = threadIdx.x;

    if (blk < SORT_BLOCKS) {                      // ---- place_slack ----
        for (int i = tid; i < NCB; i += 256) h[i] = 0;
        __syncthreads();
        int base = blk * EB;
        #pragma unroll
        for (int k = 0; k < EB / 256; ++k) {
            int e = base + k * 256 + tid;
            if (e < N_EDGES) {
                int key = eidx[N_EDGES + e] * N_REL + etype[e];
                atomicAdd(&h[key >> CB_BITS], 1u);
            }
        }
        __syncthreads();
        for (int i = tid; i < NCB; i += 256)
            cur[i] = atomicAdd(&ccur[i], h[i]);   // reserve private run
        __syncthreads();
        #pragma unroll
        for (int k = 0; k < EB / 256; ++k) {
            int e = base + k * 256 + tid;
            if (e < N_EDGES) {
                unsigned int src = (unsigned int)eidx[e];
                int key = eidx[N_EDGES + e] * N_REL + etype[e];
                int cb = key >> CB_BITS;
                unsigned int klo = (unsigned int)(key & (KEYS_PER_CB - 1));
                unsigned int pos = atomicAdd(&cur[cb], 1u);
                ebuf[(size_t)cb * CAP + pos] = (klo << 16) | src;
            }
        }
    } else if (blk < XB_BASE) {                   // ---- compute_wt ----
        int t = (blk - WT_BASE) * 256 + tid;
        int i = t & (DIM - 1);
        int r = (t >> 7) % (N_REL + 1);
        int o = t / (DIM * (N_REL + 1));
        float v;
        if (r < N_REL) {
            v = 0.f;
            #pragma unroll
            for (int b = 0; b < N_BASIS; ++b)
                v += bw[r * N_BASIS + b] * bases[((size_t)b * DIM + i) * DIM + o];
        } else {
            v = selfW[o * DIM + i];
        }
        Wt[(size_t)o * KTOT + r * DIM + i] = f2bf(v);
    } else if (blk < NT_BASE) {                   // ---- build_xb (x8 vectorized) ----
        int idx = (blk - XB_BASE) * 256 + tid;    // [0, 800000)
        const float4* x4 = (const float4*)x;
        float4 a = x4[idx * 2], b = x4[idx * 2 + 1];
        ushort8v o;
        o[0] = f2bf(a.x); o[1] = f2bf(a.y); o[2] = f2bf(a.z); o[3] = f2bf(a.w);
        o[4] = f2bf(b.x); o[5] = f2bf(b.y); o[6] = f2bf(b.z); o[7] = f2bf(b.w);
        *(ushort8v*)(xb + (size_t)idx * 8) = o;
    } else {                                      // ---- build_normT ----
        int d0 = (blk - NT_BASE) * 64;
        #pragma unroll
        for (int q = 0; q < 5; ++q) {
            int idx = q * 256 + tid;              // 1280 = 20 r x 64 d
            int r = idx >> 6, dc = idx & 63;
            if (r < N_REL && d0 + dc < N_NODES)
                tile[dc][r] = 1.0f / norm[(size_t)r * N_NODES + d0 + dc];
        }
        __syncthreads();
        #pragma unroll
        for (int q = 0; q < 5; ++q) {
            int idx = q * 256 + tid;
            int d = idx / 20, r = idx - d * 20;
            if (idx < 1280 && d0 + d < N_NODES)
                normT[(size_t)(d0 + d) * 20 + r] = tile[d][r];
        }
    }
}

// scan_fills: exclusive-scan the 245 bucket fills -> dense bases
__global__ __launch_bounds__(256) void scan_fills(const unsigned int* __restrict__ ccur,
                                                  unsigned int* __restrict__ cbase,
                                                  unsigned int* __restrict__ binstart) {
    __shared__ unsigned int lds[256];
    int t = threadIdx.x;
    unsigned int v = (t < NCB) ? ccur[t] : 0u;
    lds[t] = v; __syncthreads();
    for (int off = 1; off < 256; off <<= 1) {
        unsigned int a = (t >= off) ? lds[t - off] : 0u;
        __syncthreads();
        lds[t] += a;
        __syncthreads();
    }
    unsigned int excl = lds[t] - v;
    if (t < NCB) cbase[t] = excl;
    if (t == NCB - 1) cbase[NCB] = lds[t];        // == N_EDGES
    if (t == 0) binstart[NBINS] = N_EDGES;        // global sentinel
}

__global__ __launch_bounds__(256) void place_fine(const unsigned int* __restrict__ cbase,
                                                  const unsigned int* __restrict__ ccur,
                                                  const unsigned int* __restrict__ ebuf,
                                                  unsigned int* __restrict__ sorted,
                                                  unsigned int* __restrict__ binstart) {
    __shared__ unsigned int h[KEYS_PER_CB];
    __shared__ unsigned int cur[KEYS_PER_CB];
    __shared__ unsigned int pscan[256];
    int b = blockIdx.x, t = threadIdx.x;
    unsigned int fill = ccur[b];
    unsigned int s = cbase[b];                    // dense base in sorted
    const unsigned int* src = ebuf + (size_t)b * CAP;
    #pragma unroll
    for (int q = 0; q < 16; ++q) h[t * 16 + q] = 0;
    __syncthreads();
    for (unsigned int j = t; j < fill; j += 256)
        atomicAdd(&h[src[j] >> 16], 1u);
    __syncthreads();
    unsigned int c[16], part = 0;
    #pragma unroll
    for (int q = 0; q < 16; ++q) { c[q] = h[t * 16 + q]; part += c[q]; }
    pscan[t] = part; __syncthreads();
    for (int off = 1; off < 256; off <<= 1) {
        unsigned int a = (t >= off) ? pscan[t - off] : 0u;
        __syncthreads();
        pscan[t] += a;
        __syncthreads();
    }
    unsigned int run = pscan[t] - part;
    #pragma unroll
    for (int q = 0; q < 16; ++q) {
        int key = b * KEYS_PER_CB + t * 16 + q;
        if (key < NBINS) binstart[key] = s + run;
        cur[t * 16 + q] = run;
        run += c[q];
    }
    __syncthreads();
    for (unsigned int j = t; j < fill; j += 256) {
        unsigned int v = src[j];
        unsigned int klo = v >> 16;
        unsigned int key = (unsigned int)b * KEYS_PER_CB + klo;
        unsigned int r = key % N_REL;             // rel from key (magic-mul div)
        unsigned int pos = s + atomicAdd(&cur[klo], 1u);
        sorted[pos] = (r << 16) | (v & 0xFFFFu);  // payload: rel | src
    }
}

// ---------- reduce: wave per dst, register-resident edge stream, 8-wide load pipeline ----------
__global__ __launch_bounds__(256) void reduce_all(const unsigned int* __restrict__ sorted,
                                                  const unsigned int* __restrict__ binstart,
                                                  const unsigned int* __restrict__ xb32,
                                                  const float* __restrict__ normT,
                                                  unsigned int* __restrict__ agg32,
                                                  int r0, int rch, int rowK2) {
    int wv = threadIdx.x >> 6, lane = threadIdx.x & 63;
    int dst = blockIdx.x * 4 + wv;
    if (dst >= N_NODES) return;
    unsigned int nbase = (unsigned int)dst * N_REL;
    int rE  = r0 + rch;                          // exclusive end (may include slot 20 = self)
    int rEe = (rE < N_REL) ? rE : N_REL;         // exclusive end of edge-rels

    float nrm = (lane < rEe - r0) ? normT[nbase + r0 + lane] : 0.f;
    unsigned int bs = binstart[nbase + r0];
    unsigned int be = binstart[nbase + rEe];

    int cur_r = r0;
    float a0 = 0.f, a1 = 0.f;
    unsigned int pk, zz;
    asm("v_cvt_pk_bf16_f32 %0, %1, %2" : "=v"(zz) : "v"(0.f), "v"(0.f));

    #define FLUSH_ROW(RR, PKV) \
        agg32[(size_t)dst * rowK2 + ((RR) - r0) * 64 + lane] = (PKV)

    #define PROCESS(E, W) do {                                               \
        int rr_ = (int)((E) >> 16);                                          \
        if (rr_ != cur_r) {                                                  \
            float inv_ = __shfl(nrm, cur_r - r0);                            \
            float s0_ = a0 * inv_, s1_ = a1 * inv_;                          \
            asm("v_cvt_pk_bf16_f32 %0, %1, %2" : "=v"(pk) : "v"(s0_), "v"(s1_)); \
            FLUSH_ROW(cur_r, pk);                                            \
            for (int z_ = cur_r + 1; z_ < rr_; ++z_) FLUSH_ROW(z_, zz);      \
            a0 = 0.f; a1 = 0.f; cur_r = rr_;                                 \
        }                                                                    \
        a0 += bf2f((unsigned short)((W) & 0xFFFF));                          \
        a1 += bf2f((unsigned short)((W) >> 16));                             \
    } while (0)

    for (unsigned int j = bs; j < be; ) {
        unsigned int rem = be - j;
        int chunk = (rem < 64u) ? (int)rem : 64;
        unsigned int ent = (lane < chunk) ? sorted[j + lane] : 0u;  // wave-wide metadata load
        int u = 0;
        for (; u + 8 <= chunk; u += 8) {         // 8 independent gathers in flight
            unsigned int e0 = __shfl(ent, u),     e1 = __shfl(ent, u + 1);
            unsigned int e2 = __shfl(ent, u + 2), e3 = __shfl(ent, u + 3);
            unsigned int e4 = __shfl(ent, u + 4), e5 = __shfl(ent, u + 5);
            unsigned int e6 = __shfl(ent, u + 6), e7 = __shfl(ent, u + 7);
            unsigned int w0 = xb32[(size_t)(e0 & 0xFFFF) * 64 + lane];
            unsigned int w1 = xb32[(size_t)(e1 & 0xFFFF) * 64 + lane];
            unsigned int w2 = xb32[(size_t)(e2 & 0xFFFF) * 64 + lane];
            unsigned int w3 = xb32[(size_t)(e3 & 0xFFFF) * 64 + lane];
            unsigned int w4 = xb32[(size_t)(e4 & 0xFFFF) * 64 + lane];
            unsigned int w5 = xb32[(size_t)(e5 & 0xFFFF) * 64 + lane];
            unsigned int w6 = xb32[(size_t)(e6 & 0xFFFF) * 64 + lane];
            unsigned int w7 = xb32[(size_t)(e7 & 0xFFFF) * 64 + lane];
            PROCESS(e0, w0); PROCESS(e1, w1); PROCESS(e2, w2); PROCESS(e3, w3);
            PROCESS(e4, w4); PROCESS(e5, w5); PROCESS(e6, w6); PROCESS(e7, w7);
        }
        for (; u < chunk; ++u) {
            unsigned int e = __shfl(ent, u);
            unsigned int w = xb32[(size_t)(e & 0xFFFF) * 64 + lane];
            PROCESS(e, w);
        }
        j += chunk;
    }
    {
        float inv = __shfl(nrm, cur_r - r0);
        float s0 = a0 * inv, s1 = a1 * inv;
        asm("v_cvt_pk_bf16_f32 %0, %1, %2" : "=v"(pk) : "v"(s0), "v"(s1));
        FLUSH_ROW(cur_r, pk);
        for (int z = cur_r + 1; z < rEe; ++z) FLUSH_ROW(z, zz);
    }
    if (rE > N_REL) {                            // self-loop slot (virtual rel 20)
        unsigned int w = xb32[(size_t)dst * 64 + lane];
        float s0 = bf2f((unsigned short)(w & 0xFFFF));
        float s1 = bf2f((unsigned short)(w >> 16));
        asm("v_cvt_pk_bf16_f32 %0, %1, %2" : "=v"(pk) : "v"(s0), "v"(s1));
        agg32[(size_t)dst * rowK2 + (N_REL - r0) * 64 + lane] = pk;
    }
    #undef PROCESS
    #undef FLUSH_ROW
}

// ---------- MFMA GEMM: BK=32 dbuf (24 KB LDS -> 6 blocks/CU), counted vmcnt(3) ----------
// out[n][o] (+)= sum_k Wt_sub[o*KTOT+k] * Bsrc[n*K+k].  Tile: 64 n x 128 o.
// LDS rows = 32 shorts (64 B); 16B slot kq holds global chunk kq ^ swz(row),
// swz(row) = (row ^ row>>2) & 3  -> exact 2-way bank aliasing (free).
__global__ __launch_bounds__(256) void gemm_bf(const unsigned short* __restrict__ Wt_sub,
                                               const unsigned short* __restrict__ Bsrc,
                                               int K,
                                               float* __restrict__ C,
                                               int acc_mode) {
    __shared__ __align__(16) unsigned short WsL[2][128 * BKG];   // 16 KB
    __shared__ __align__(16) unsigned short AsL[2][64 * BKG];    // 8 KB

    const int tid  = threadIdx.x;
    const int lane = tid & 63;
    const int wv   = tid >> 6;
    const int wo   = wv >> 1;                    // o-half (0..1): 64 o rows
    const int wn   = wv & 1;                     // n-half (0..1): 32 n rows
    const int r16  = lane & 15;
    const int hi4  = lane >> 4;
    const int nb   = blockIdx.x * 64;

    #define SWZ(R) (((R) ^ ((R) >> 2)) & 3)

    // staging: per issue, wave fills 16 rows (lane>>2 = row-in-group, lane&3 = 16B slot)
    const int srow = lane >> 2;
    const int kq   = lane & 3;
    const unsigned short* sW[2];
    #pragma unroll
    for (int i = 0; i < 2; ++i) {
        int row = wv * 16 + i * 64 + srow;
        sW[i] = Wt_sub + (size_t)row * KTOT + ((kq ^ SWZ(row)) << 3);
    }
    const unsigned short* sA;
    {
        int row = wv * 16 + srow;
        int gn = nb + row; if (gn >= N_NODES) gn = N_NODES - 1;   // clamp (dup rows unused)
        sA = Bsrc + (size_t)gn * K + ((kq ^ SWZ(row)) << 3);
    }

    #define GL16(SRC, DST) __builtin_amdgcn_global_load_lds( \
        (const __attribute__((address_space(1))) void*)(SRC), \
        (__attribute__((address_space(3))) void*)(DST), 16, 0, 0)

    #define STAGE(B) do {                                                  \
        GL16(sW[0], &WsL[B][(wv * 16) * BKG]);                             \
        GL16(sW[1], &WsL[B][(wv * 16 + 64) * BKG]);                        \
        GL16(sA,    &AsL[B][(wv * 16) * BKG]);                             \
        sW[0] += BKG; sW[1] += BKG; sA += BKG;                             \
    } while (0)

    f32x4 acc[2][4];
    #pragma unroll
    for (int g = 0; g < 2; ++g)
        #pragma unroll
        for (int of = 0; of < 4; ++of) acc[g][of] = (f32x4){0.f, 0.f, 0.f, 0.f};

    const int NT = K / BKG;
    STAGE(0);                                    // tile 0 in flight

    int cur = 0;
    for (int t = 0; t < NT; ++t) {
        if (t + 1 < NT) {
            STAGE(cur ^ 1);                      // issue tile t+1 (3 loads; stay in flight)
            asm volatile("s_waitcnt vmcnt(3)" ::: "memory");   // tile t landed; t+1 pending
        } else {
            asm volatile("s_waitcnt vmcnt(0)" ::: "memory");
        }
        __builtin_amdgcn_s_barrier();            // all waves' tile-t DMA visible
        __builtin_amdgcn_sched_barrier(0);

        const unsigned short* Wb = WsL[cur];
        const unsigned short* Ab = AsL[cur];
        bf16x8 bfr[2];
        #pragma unroll
        for (int q = 0; q < 2; ++q) {
            int nr = wn * 32 + q * 16 + r16;
            bfr[q] = *(const bf16x8*)&Ab[nr * BKG + ((hi4 ^ SWZ(nr)) << 3)];
        }
        #pragma unroll
        for (int of = 0; of < 4; ++of) {
            int ro = wo * 64 + of * 16 + r16;
            bf16x8 afr = *(const bf16x8*)&Wb[ro * BKG + ((hi4 ^ SWZ(ro)) << 3)];
            acc[0][of] = __builtin_amdgcn_mfma_f32_16x16x32_bf16(afr, bfr[0], acc[0][of], 0, 0, 0);
            acc[1][of] = __builtin_amdgcn_mfma_f32_16x16x32_bf16(afr, bfr[1], acc[1][of], 0, 0, 0);
        }
        __builtin_amdgcn_sched_barrier(0);
        __builtin_amdgcn_s_barrier();            // reads of buf[cur] done before next STAGE(cur)
        cur ^= 1;
    }
    #undef STAGE
    #undef GL16
    #undef SWZ

    // epilogue: D col = r16 -> n, row = hi4*4+reg -> o (within frag)
    #pragma unroll
    for (int g = 0; g < 2; ++g) {
        int n = nb + wn * 32 + g * 16 + r16;
        if (n < N_NODES) {
            #pragma unroll
            for (int of = 0; of < 4; ++of) {
                float* p = C + (size_t)n * DIM + wo * 64 + of * 16 + hi4 * 4;
                if (acc_mode) {
                    p[0] += acc[g][of].x; p[1] += acc[g][of].y;
                    p[2] += acc[g][of].z; p[3] += acc[g][of].w;
                } else {
                    f32x4 v = acc[g][of];
                    *(float4*)p = (float4){v.x, v.y, v.z, v.w};
                }
            }
        }
    }
}

extern "C" void kernel_launch(void* const* d_in, const int* in_sizes, int n_in,
                              void* d_out, int out_size, void* d_ws, size_t ws_size,
                              hipStream_t stream) {
    const float* x     = (const float*)d_in[0];
    const int*   eidx  = (const int*)d_in[1];
    const int*   etype = (const int*)d_in[2];
    const float* norm  = (const float*)d_in[3];
    const float* selfW = (const float*)d_in[4];
    const float* bases = (const float*)d_in[5];
    const float* bw    = (const float*)d_in[6];
    float* out = (float*)d_out;

    // ---- workspace: fixed ~37 MB, agg takes the rest (chunked) ----
    char* p = (char*)d_ws;
    auto alloc = [&](size_t bytes) { char* q = p; p += (bytes + 255) & ~(size_t)255; return q; };
    unsigned short* Wt       = (unsigned short*)alloc((size_t)DIM * KTOT * 2);   // 0.69 MB
    unsigned short* xb       = (unsigned short*)alloc((size_t)N_NODES * DIM * 2);// 12.8 MB
    float*          normT    = (float*)alloc((size_t)N_NODES * N_REL * 4);       // 4.0 MB
    unsigned int*   sorted   = (unsigned int*)alloc((size_t)N_EDGES * 4);        // 6.4 MB
    unsigned int*   binstart = (unsigned int*)alloc((size_t)(NBINS + 1) * 4);    // 4.0 MB
    unsigned int*   ebuf     = (unsigned int*)alloc((size_t)NCB * CAP * 4);      // 8.0 MB slack
    unsigned int*   cbase    = (unsigned int*)alloc((size_t)(NCB + 1) * 4);
    unsigned int*   ccur     = (unsigned int*)alloc((size_t)NCB * 4);
    unsigned int*   agg32    = (unsigned int*)p;                                 // rest
    size_t fixed = (size_t)(p - (char*)d_ws);
    size_t per_rel = (size_t)N_NODES * DIM * 2;                                  // 12.8 MB
    // rch=7: agg chunk = 89.6 MB -> L3-resident producer->consumer handoff
    int rch = 7;
    {
        size_t avail = (ws_size > fixed) ? ws_size - fixed : 0;
        int m = (int)(avail / per_rel);
        if (m < rch) rch = m;
        if (rch < 1) rch = 1;
    }

    // 1+2a. merged prep + slack-place (one dispatch; sort blocks scheduled first)
    hipMemsetAsync(ccur, 0, (size_t)NCB * 4, stream);
    prep_place<<<dim3(PP_GRID), dim3(256), 0, stream>>>(
        x, eidx, etype, bases, bw, selfW, norm, Wt, xb, normT, ccur, ebuf);

    // 2b. dense bases + fine place
    scan_fills<<<dim3(1), dim3(256), 0, stream>>>(ccur, cbase, binstart);
    place_fine<<<dim3(NCB), dim3(256), 0, stream>>>(cbase, ccur, ebuf, sorted, binstart);

    // 3. per chunk of rch rels (21 virtual rels incl. self): reduce + GEMM (L3-hot handoff)
    int gblocks = (N_NODES + 63) / 64;
    for (int r0 = 0; r0 < N_REL + 1; r0 += rch) {
        int rchA = (rch < N_REL + 1 - r0) ? rch : (N_REL + 1 - r0);
        reduce_all<<<dim3((N_NODES + 3) / 4), dim3(256), 0, stream>>>(
            sorted, binstart, (const unsigned int*)xb, normT, agg32, r0, rchA, rchA * 64);
        gemm_bf<<<dim3(gblocks), dim3(256), 0, stream>>>(
            Wt + r0 * DIM, (const unsigned short*)agg32, rchA * DIM, out, r0 > 0);
    }
}

// Round 16
// 250.922 us; speedup vs baseline: 5.5321x; 1.1053x over previous
//
#include <hip/hip_runtime.h>
#include <hip/hip_bf16.h>

#define N_NODES 50000
#define N_EDGES 1600000
#define N_REL   20
#define N_BASIS 16
#define DIM     128
#define KTOT    ((N_REL + 1) * DIM)      // 2688 : Wt row stride (20 rels + self)

#define NBINS   (N_NODES * N_REL)        // 1,000,000 : key = dst*20 + r  (dst-major)
#define CB_BITS 12
#define KEYS_PER_CB (1 << CB_BITS)                            // 4096
#define NCB  ((NBINS + KEYS_PER_CB - 1) >> CB_BITS)           // 245
#define CAP  8192                                             // slack bucket capacity (exp 6554)
#define EB   4096
#define SORT_BLOCKS ((N_EDGES + EB - 1) / EB)                 // 391
#define BKG  32                                               // GEMM K-tile (24 KB LDS dbuf)

// prep_place block-range bases
#define WT_TOTAL  (DIM * (N_REL + 1) * DIM)                   // 344064
#define WT_BLOCKS (WT_TOTAL / 256)                            // 1344
#define XB_BLOCKS (N_NODES * DIM / 8 / 256)                   // 3125
#define NT_BLOCKS ((N_NODES + 63) / 64)                       // 782
#define WT_BASE   SORT_BLOCKS
#define XB_BASE   (WT_BASE + WT_BLOCKS)
#define NT_BASE   (XB_BASE + XB_BLOCKS)
#define PP_GRID   (NT_BASE + NT_BLOCKS)                       // 5642

typedef __attribute__((ext_vector_type(8))) short          bf16x8;
typedef __attribute__((ext_vector_type(4))) float          f32x4;
typedef __attribute__((ext_vector_type(8))) unsigned short ushort8v;

static __device__ __forceinline__ unsigned short f2bf(float f) {
    union { float f; unsigned int u; } v; v.f = f;
    unsigned int r = (v.u + 0x7FFFu + ((v.u >> 16) & 1u)) >> 16;   // RNE
    return (unsigned short)r;
}
static __device__ __forceinline__ float bf2f(unsigned short s) {
    union { unsigned int u; float f; } v; v.u = ((unsigned int)s) << 16;
    return v.f;
}

// ---------- merged prep + slack-place (independent work, one dispatch) ----------
__global__ __launch_bounds__(256) void prep_place(const float* __restrict__ x,
                                                  const int* __restrict__ eidx,
                                                  const int* __restrict__ etype,
                                                  const float* __restrict__ bases,
                                                  const float* __restrict__ bw,
                                                  const float* __restrict__ selfW,
                                                  const float* __restrict__ norm,
                                                  unsigned short* __restrict__ Wt,
                                                  unsigned short* __restrict__ xb,
                                                  float* __restrict__ normT,
                                                  unsigned int* __restrict__ ccur,
                                                  unsigned int* __restrict__ ebuf) {
    __shared__ unsigned int h[NCB];
    __shared__ unsigned int cur[NCB];
    __shared__ float tile[64][21];
    const int blk = blockIdx.x, tid = threadIdx.x;

    if (blk < SORT_BLOCKS) {                      // ---- place_slack ----
        for (int i = tid; i < NCB; i += 256) h[i] = 0;
        __syncthreads();
        int base = blk * EB;
        #pragma unroll
        for (int k = 0; k < EB / 256; ++k) {
            int e = base + k * 256 + tid;
            if (e < N_EDGES) {
                int key = eidx[N_EDGES + e] * N_REL + etype[e];
                atomicAdd(&h[key >> CB_BITS], 1u);
            }
        }
        __syncthreads();
        for (int i = tid; i < NCB; i += 256)
            cur[i] = atomicAdd(&ccur[i], h[i]);   // reserve private run
        __syncthreads();
        #pragma unroll
        for (int k = 0; k < EB / 256; ++k) {
            int e = base + k * 256 + tid;
            if (e < N_EDGES) {
                unsigned int src = (unsigned int)eidx[e];
                int key = eidx[N_EDGES + e] * N_REL + etype[e];
                int cb = key >> CB_BITS;
                unsigned int klo = (unsigned int)(key & (KEYS_PER_CB - 1));
                unsigned int pos = atomicAdd(&cur[cb], 1u);
                ebuf[(size_t)cb * CAP + pos] = (klo << 16) | src;
            }
        }
    } else if (blk < XB_BASE) {                   // ---- compute_wt ----
        int t = (blk - WT_BASE) * 256 + tid;
        int i = t & (DIM - 1);
        int r = (t >> 7) % (N_REL + 1);
        int o = t / (DIM * (N_REL + 1));
        float v;
        if (r < N_REL) {
            v = 0.f;
            #pragma unroll
            for (int b = 0; b < N_BASIS; ++b)
                v += bw[r * N_BASIS + b] * bases[((size_t)b * DIM + i) * DIM + o];
        } else {
            v = selfW[o * DIM + i];
        }
        Wt[(size_t)o * KTOT + r * DIM + i] = f2bf(v);
    } else if (blk < NT_BASE) {                   // ---- build_xb (x8 vectorized) ----
        int idx = (blk - XB_BASE) * 256 + tid;    // [0, 800000)
        const float4* x4 = (const float4*)x;
        float4 a = x4[idx * 2], b = x4[idx * 2 + 1];
        ushort8v o;
        o[0] = f2bf(a.x); o[1] = f2bf(a.y); o[2] = f2bf(a.z); o[3] = f2bf(a.w);
        o[4] = f2bf(b.x); o[5] = f2bf(b.y); o[6] = f2bf(b.z); o[7] = f2bf(b.w);
        *(ushort8v*)(xb + (size_t)idx * 8) = o;
    } else {                                      // ---- build_normT ----
        int d0 = (blk - NT_BASE) * 64;
        #pragma unroll
        for (int q = 0; q < 5; ++q) {
            int idx = q * 256 + tid;              // 1280 = 20 r x 64 d
            int r = idx >> 6, dc = idx & 63;
            if (r < N_REL && d0 + dc < N_NODES)
                tile[dc][r] = 1.0f / norm[(size_t)r * N_NODES + d0 + dc];
        }
        __syncthreads();
        #pragma unroll
        for (int q = 0; q < 5; ++q) {
            int idx = q * 256 + tid;
            int d = idx / 20, r = idx - d * 20;
            if (idx < 1280 && d0 + d < N_NODES)
                normT[(size_t)(d0 + d) * 20 + r] = tile[d][r];
        }
    }
}

// scan_fills: exclusive-scan the 245 bucket fills -> dense bases
__global__ __launch_bounds__(256) void scan_fills(const unsigned int* __restrict__ ccur,
                                                  unsigned int* __restrict__ cbase,
                                                  unsigned int* __restrict__ binstart) {
    __shared__ unsigned int lds[256];
    int t = threadIdx.x;
    unsigned int v = (t < NCB) ? ccur[t] : 0u;
    lds[t] = v; __syncthreads();
    for (int off = 1; off < 256; off <<= 1) {
        unsigned int a = (t >= off) ? lds[t - off] : 0u;
        __syncthreads();
        lds[t] += a;
        __syncthreads();
    }
    unsigned int excl = lds[t] - v;
    if (t < NCB) cbase[t] = excl;
    if (t == NCB - 1) cbase[NCB] = lds[t];        // == N_EDGES
    if (t == 0) binstart[NBINS] = N_EDGES;        // global sentinel
}

// place_fine: 1024 threads (245 blocks are CU-sparse; wider block = 4x issue slots)
__global__ __launch_bounds__(1024) void place_fine(const unsigned int* __restrict__ cbase,
                                                   const unsigned int* __restrict__ ccur,
                                                   const unsigned int* __restrict__ ebuf,
                                                   unsigned int* __restrict__ sorted,
                                                   unsigned int* __restrict__ binstart) {
    __shared__ unsigned int h[KEYS_PER_CB];
    __shared__ unsigned int cur[KEYS_PER_CB];
    __shared__ unsigned int pscan[1024];
    int b = blockIdx.x, t = threadIdx.x;
    unsigned int fill = ccur[b];
    unsigned int s = cbase[b];                    // dense base in sorted
    const unsigned int* src = ebuf + (size_t)b * CAP;
    #pragma unroll
    for (int q = 0; q < 4; ++q) h[t * 4 + q] = 0;
    __syncthreads();
    for (unsigned int j = t; j < fill; j += 1024)
        atomicAdd(&h[src[j] >> 16], 1u);
    __syncthreads();
    unsigned int c[4], part = 0;
    #pragma unroll
    for (int q = 0; q < 4; ++q) { c[q] = h[t * 4 + q]; part += c[q]; }
    pscan[t] = part; __syncthreads();
    for (int off = 1; off < 1024; off <<= 1) {
        unsigned int a = (t >= off) ? pscan[t - off] : 0u;
        __syncthreads();
        pscan[t] += a;
        __syncthreads();
    }
    unsigned int run = pscan[t] - part;
    #pragma unroll
    for (int q = 0; q < 4; ++q) {
        int key = b * KEYS_PER_CB + t * 4 + q;
        if (key < NBINS) binstart[key] = s + run;
        cur[t * 4 + q] = run;
        run += c[q];
    }
    __syncthreads();
    for (unsigned int j = t; j < fill; j += 1024) {
        unsigned int v = src[j];
        unsigned int klo = v >> 16;
        unsigned int key = (unsigned int)b * KEYS_PER_CB + klo;
        unsigned int r = key % N_REL;             // rel from key (magic-mul div)
        unsigned int pos = s + atomicAdd(&cur[klo], 1u);
        sorted[pos] = (r << 16) | (v & 0xFFFFu);  // payload: rel | src
    }
}

// ---------- reduce: wave per dst, register-resident edge stream, 8-wide load pipeline ----------
__global__ __launch_bounds__(256) void reduce_all(const unsigned int* __restrict__ sorted,
                                                  const unsigned int* __restrict__ binstart,
                                                  const unsigned int* __restrict__ xb32,
                                                  const float* __restrict__ normT,
                                                  unsigned int* __restrict__ agg32,
                                                  int r0, int rch, int rowK2) {
    int wv = threadIdx.x >> 6, lane = threadIdx.x & 63;
    int dst = blockIdx.x * 4 + wv;
    if (dst >= N_NODES) return;
    unsigned int nbase = (unsigned int)dst * N_REL;
    int rE  = r0 + rch;                          // exclusive end (may include slot 20 = self)
    int rEe = (rE < N_REL) ? rE : N_REL;         // exclusive end of edge-rels

    float nrm = (lane < rEe - r0) ? normT[nbase + r0 + lane] : 0.f;
    unsigned int bs = binstart[nbase + r0];
    unsigned int be = binstart[nbase + rEe];

    int cur_r = r0;
    float a0 = 0.f, a1 = 0.f;
    unsigned int pk, zz;
    asm("v_cvt_pk_bf16_f32 %0, %1, %2" : "=v"(zz) : "v"(0.f), "v"(0.f));

    #define FLUSH_ROW(RR, PKV) \
        agg32[(size_t)dst * rowK2 + ((RR) - r0) * 64 + lane] = (PKV)

    #define PROCESS(E, W) do {                                               \
        int rr_ = (int)((E) >> 16);                                          \
        if (rr_ != cur_r) {                                                  \
            float inv_ = __shfl(nrm, cur_r - r0);                            \
            float s0_ = a0 * inv_, s1_ = a1 * inv_;                          \
            asm("v_cvt_pk_bf16_f32 %0, %1, %2" : "=v"(pk) : "v"(s0_), "v"(s1_)); \
            FLUSH_ROW(cur_r, pk);                                            \
            for (int z_ = cur_r + 1; z_ < rr_; ++z_) FLUSH_ROW(z_, zz);      \
            a0 = 0.f; a1 = 0.f; cur_r = rr_;                                 \
        }                                                                    \
        a0 += bf2f((unsigned short)((W) & 0xFFFF));                          \
        a1 += bf2f((unsigned short)((W) >> 16));                             \
    } while (0)

    for (unsigned int j = bs; j < be; ) {
        unsigned int rem = be - j;
        int chunk = (rem < 64u) ? (int)rem : 64;
        unsigned int ent = (lane < chunk) ? sorted[j + lane] : 0u;  // wave-wide metadata load
        int u = 0;
        for (; u + 8 <= chunk; u += 8) {         // 8 independent gathers in flight
            unsigned int e0 = __shfl(ent, u),     e1 = __shfl(ent, u + 1);
            unsigned int e2 = __shfl(ent, u + 2), e3 = __shfl(ent, u + 3);
            unsigned int e4 = __shfl(ent, u + 4), e5 = __shfl(ent, u + 5);
            unsigned int e6 = __shfl(ent, u + 6), e7 = __shfl(ent, u + 7);
            unsigned int w0 = xb32[(size_t)(e0 & 0xFFFF) * 64 + lane];
            unsigned int w1 = xb32[(size_t)(e1 & 0xFFFF) * 64 + lane];
            unsigned int w2 = xb32[(size_t)(e2 & 0xFFFF) * 64 + lane];
            unsigned int w3 = xb32[(size_t)(e3 & 0xFFFF) * 64 + lane];
            unsigned int w4 = xb32[(size_t)(e4 & 0xFFFF) * 64 + lane];
            unsigned int w5 = xb32[(size_t)(e5 & 0xFFFF) * 64 + lane];
            unsigned int w6 = xb32[(size_t)(e6 & 0xFFFF) * 64 + lane];
            unsigned int w7 = xb32[(size_t)(e7 & 0xFFFF) * 64 + lane];
            PROCESS(e0, w0); PROCESS(e1, w1); PROCESS(e2, w2); PROCESS(e3, w3);
            PROCESS(e4, w4); PROCESS(e5, w5); PROCESS(e6, w6); PROCESS(e7, w7);
        }
        for (; u < chunk; ++u) {
            unsigned int e = __shfl(ent, u);
            unsigned int w = xb32[(size_t)(e & 0xFFFF) * 64 + lane];
            PROCESS(e, w);
        }
        j += chunk;
    }
    {
        float inv = __shfl(nrm, cur_r - r0);
        float s0 = a0 * inv, s1 = a1 * inv;
        asm("v_cvt_pk_bf16_f32 %0, %1, %2" : "=v"(pk) : "v"(s0), "v"(s1));
        FLUSH_ROW(cur_r, pk);
        for (int z = cur_r + 1; z < rEe; ++z) FLUSH_ROW(z, zz);
    }
    if (rE > N_REL) {                            // self-loop slot (virtual rel 20)
        unsigned int w = xb32[(size_t)dst * 64 + lane];
        float s0 = bf2f((unsigned short)(w & 0xFFFF));
        float s1 = bf2f((unsigned short)(w >> 16));
        asm("v_cvt_pk_bf16_f32 %0, %1, %2" : "=v"(pk) : "v"(s0), "v"(s1));
        agg32[(size_t)dst * rowK2 + (N_REL - r0) * 64 + lane] = pk;
    }
    #undef PROCESS
    #undef FLUSH_ROW
}

// ---------- MFMA GEMM: BK=32 dbuf (24 KB LDS -> 6 blocks/CU), counted vmcnt(3) ----------
// out[n][o] (+)= sum_k Wt_sub[o*KTOT+k] * Bsrc[n*K+k].  Tile: 64 n x 128 o.
// LDS rows = 32 shorts (64 B); 16B slot kq holds global chunk kq ^ swz(row),
// swz(row) = (row ^ row>>2) & 3  -> exact 2-way bank aliasing (free).
__global__ __launch_bounds__(256) void gemm_bf(const unsigned short* __restrict__ Wt_sub,
                                               const unsigned short* __restrict__ Bsrc,
                                               int K,
                                               float* __restrict__ C,
                                               int acc_mode) {
    __shared__ __align__(16) unsigned short WsL[2][128 * BKG];   // 16 KB
    __shared__ __align__(16) unsigned short AsL[2][64 * BKG];    // 8 KB

    const int tid  = threadIdx.x;
    const int lane = tid & 63;
    const int wv   = tid >> 6;
    const int wo   = wv >> 1;                    // o-half (0..1): 64 o rows
    const int wn   = wv & 1;                     // n-half (0..1): 32 n rows
    const int r16  = lane & 15;
    const int hi4  = lane >> 4;
    const int nb   = blockIdx.x * 64;

    #define SWZ(R) (((R) ^ ((R) >> 2)) & 3)

    // staging: per issue, wave fills 16 rows (lane>>2 = row-in-group, lane&3 = 16B slot)
    const int srow = lane >> 2;
    const int kq   = lane & 3;
    const unsigned short* sW[2];
    #pragma unroll
    for (int i = 0; i < 2; ++i) {
        int row = wv * 16 + i * 64 + srow;
        sW[i] = Wt_sub + (size_t)row * KTOT + ((kq ^ SWZ(row)) << 3);
    }
    const unsigned short* sA;
    {
        int row = wv * 16 + srow;
        int gn = nb + row; if (gn >= N_NODES) gn = N_NODES - 1;   // clamp (dup rows unused)
        sA = Bsrc + (size_t)gn * K + ((kq ^ SWZ(row)) << 3);
    }

    #define GL16(SRC, DST) __builtin_amdgcn_global_load_lds( \
        (const __attribute__((address_space(1))) void*)(SRC), \
        (__attribute__((address_space(3))) void*)(DST), 16, 0, 0)

    #define STAGE(B) do {                                                  \
        GL16(sW[0], &WsL[B][(wv * 16) * BKG]);                             \
        GL16(sW[1], &WsL[B][(wv * 16 + 64) * BKG]);                        \
        GL16(sA,    &AsL[B][(wv * 16) * BKG]);                             \
        sW[0] += BKG; sW[1] += BKG; sA += BKG;                             \
    } while (0)

    f32x4 acc[2][4];
    #pragma unroll
    for (int g = 0; g < 2; ++g)
        #pragma unroll
        for (int of = 0; of < 4; ++of) acc[g][of] = (f32x4){0.f, 0.f, 0.f, 0.f};

    const int NT = K / BKG;
    STAGE(0);                                    // tile 0 in flight

    int cur = 0;
    for (int t = 0; t < NT; ++t) {
        if (t + 1 < NT) {
            STAGE(cur ^ 1);                      // issue tile t+1 (3 loads; stay in flight)
            asm volatile("s_waitcnt vmcnt(3)" ::: "memory");   // tile t landed; t+1 pending
        } else {
            asm volatile("s_waitcnt vmcnt(0)" ::: "memory");
        }
        __builtin_amdgcn_s_barrier();            // all waves' tile-t DMA visible
        __builtin_amdgcn_sched_barrier(0);

        const unsigned short* Wb = WsL[cur];
        const unsigned short* Ab = AsL[cur];
        bf16x8 bfr[2];
        #pragma unroll
        for (int q = 0; q < 2; ++q) {
            int nr = wn * 32 + q * 16 + r16;
            bfr[q] = *(const bf16x8*)&Ab[nr * BKG + ((hi4 ^ SWZ(nr)) << 3)];
        }
        #pragma unroll
        for (int of = 0; of < 4; ++of) {
            int ro = wo * 64 + of * 16 + r16;
            bf16x8 afr = *(const bf16x8*)&Wb[ro * BKG + ((hi4 ^ SWZ(ro)) << 3)];
            acc[0][of] = __builtin_amdgcn_mfma_f32_16x16x32_bf16(afr, bfr[0], acc[0][of], 0, 0, 0);
            acc[1][of] = __builtin_amdgcn_mfma_f32_16x16x32_bf16(afr, bfr[1], acc[1][of], 0, 0, 0);
        }
        __builtin_amdgcn_sched_barrier(0);
        __builtin_amdgcn_s_barrier();            // reads of buf[cur] done before next STAGE(cur)
        cur ^= 1;
    }
    #undef STAGE
    #undef GL16
    #undef SWZ

    // epilogue: D col = r16 -> n, row = hi4*4+reg -> o (within frag)
    #pragma unroll
    for (int g = 0; g < 2; ++g) {
        int n = nb + wn * 32 + g * 16 + r16;
        if (n < N_NODES) {
            #pragma unroll
            for (int of = 0; of < 4; ++of) {
                float* p = C + (size_t)n * DIM + wo * 64 + of * 16 + hi4 * 4;
                if (acc_mode) {
                    p[0] += acc[g][of].x; p[1] += acc[g][of].y;
                    p[2] += acc[g][of].z; p[3] += acc[g][of].w;
                } else {
                    f32x4 v = acc[g][of];
                    *(float4*)p = (float4){v.x, v.y, v.z, v.w};
                }
            }
        }
    }
}

extern "C" void kernel_launch(void* const* d_in, const int* in_sizes, int n_in,
                              void* d_out, int out_size, void* d_ws, size_t ws_size,
                              hipStream_t stream) {
    const float* x     = (const float*)d_in[0];
    const int*   eidx  = (const int*)d_in[1];
    const int*   etype = (const int*)d_in[2];
    const float* norm  = (const float*)d_in[3];
    const float* selfW = (const float*)d_in[4];
    const float* bases = (const float*)d_in[5];
    const float* bw    = (const float*)d_in[6];
    float* out = (float*)d_out;

    // ---- workspace: fixed ~37 MB, agg takes the rest (chunked) ----
    char* p = (char*)d_ws;
    auto alloc = [&](size_t bytes) { char* q = p; p += (bytes + 255) & ~(size_t)255; return q; };
    unsigned short* Wt       = (unsigned short*)alloc((size_t)DIM * KTOT * 2);   // 0.69 MB
    unsigned short* xb       = (unsigned short*)alloc((size_t)N_NODES * DIM * 2);// 12.8 MB
    float*          normT    = (float*)alloc((size_t)N_NODES * N_REL * 4);       // 4.0 MB
    unsigned int*   sorted   = (unsigned int*)alloc((size_t)N_EDGES * 4);        // 6.4 MB
    unsigned int*   binstart = (unsigned int*)alloc((size_t)(NBINS + 1) * 4);    // 4.0 MB
    unsigned int*   ebuf     = (unsigned int*)alloc((size_t)NCB * CAP * 4);      // 8.0 MB slack
    unsigned int*   cbase    = (unsigned int*)alloc((size_t)(NCB + 1) * 4);
    unsigned int*   ccur     = (unsigned int*)alloc((size_t)NCB * 4);
    unsigned int*   agg32    = (unsigned int*)p;                                 // rest
    size_t fixed = (size_t)(p - (char*)d_ws);
    size_t per_rel = (size_t)N_NODES * DIM * 2;                                  // 12.8 MB
    // rch=11: 2 chunks; agg chunk = 141 MB, still L3-resident producer->consumer handoff
    int rch = 11;
    {
        size_t avail = (ws_size > fixed) ? ws_size - fixed : 0;
        int m = (int)(avail / per_rel);
        if (m < rch) rch = m;
        if (rch < 1) rch = 1;
    }

    // 1+2a. merged prep + slack-place (one dispatch; sort blocks scheduled first)
    hipMemsetAsync(ccur, 0, (size_t)NCB * 4, stream);
    prep_place<<<dim3(PP_GRID), dim3(256), 0, stream>>>(
        x, eidx, etype, bases, bw, selfW, norm, Wt, xb, normT, ccur, ebuf);

    // 2b. dense bases + fine place (wide blocks: 245 blocks are CU-sparse)
    scan_fills<<<dim3(1), dim3(256), 0, stream>>>(ccur, cbase, binstart);
    place_fine<<<dim3(NCB), dim3(1024), 0, stream>>>(cbase, ccur, ebuf, sorted, binstart);

    // 3. per chunk of rch rels (21 virtual rels incl. self): reduce + GEMM (L3-hot handoff)
    int gblocks = (N_NODES + 63) / 64;
    for (int r0 = 0; r0 < N_REL + 1; r0 += rch) {
        int rchA = (rch < N_REL + 1 - r0) ? rch : (N_REL + 1 - r0);
        reduce_all<<<dim3((N_NODES + 3) / 4), dim3(256), 0, stream>>>(
            sorted, binstart, (const unsigned int*)xb, normT, agg32, r0, rchA, rchA * 64);
        gemm_bf<<<dim3(gblocks), dim3(256), 0, stream>>>(
            Wt + r0 * DIM, (const unsigned short*)agg32, rchA * DIM, out, r0 > 0);
    }
}